// Round 7
// baseline (421.709 us; speedup 1.0000x reference)
//
#include <hip/hip_runtime.h>
#include <hip/hip_cooperative_groups.h>
#include <math.h>

namespace cg = cooperative_groups;

#define NNODES 50000
#define NEG_SLOPE 0.2f
#define NBUCKET 391          // buckets of 128 nodes; s fits 16 bits (N < 65536)
#define CHUNK_MAX 12544      // fallback binscatter chunk (49 * 256)
#define NBIN_MAX 128

typedef unsigned short ushort8v __attribute__((ext_vector_type(8)));
typedef unsigned short ushort4v __attribute__((ext_vector_type(4)));
typedef short short8v __attribute__((ext_vector_type(8)));
typedef float f32x4 __attribute__((ext_vector_type(4)));
typedef float f32x2 __attribute__((ext_vector_type(2)));

__device__ __forceinline__ unsigned short f2bf(float f){
    unsigned u = __float_as_uint(f);
    u += 0x7fff + ((u >> 16) & 1);   // RNE; inputs finite
    return (unsigned short)(u >> 16);
}

// ---------------- prep helpers ----------------
__device__ __forceinline__ void emit_wa(const float* __restrict__ W, const float* __restrict__ a_s,
                                        const float* __restrict__ a_d, unsigned short* __restrict__ Wt,
                                        int Kin, int C, int id){
    const int n = id / Kin, k = id - n * Kin;
    float v = 0.f;
    if(n < 8){
        const int hh = n & 3;
        const float* av = (n < 4) ? a_s : a_d;
        for(int c = 0; c < C; c++) v += W[(size_t)k * (4 * C) + hh * C + c] * av[hh * C + c];
    }
    Wt[id] = f2bf(v);
}

__device__ __forceinline__ void emit_wc(const float* __restrict__ W, unsigned short* __restrict__ Wt,
                                        int Kin, int C, int id){
    const int c = id / (4 * Kin);
    const int hk = id - c * (4 * Kin);
    const int h = hk / Kin, k = hk - h * Kin;
    const float v = (c < C) ? W[(size_t)k * (4 * C) + h * C + c] * 0.25f : 0.f;
    Wt[id] = f2bf(v);
}

__device__ __forceinline__ void prep_item(int id, const float* __restrict__ x,
                                          unsigned short* __restrict__ xbf, int X4,
                                          const float* W1, const float* as1, const float* ad1,
                                          const float* W2, const float* as2, const float* ad2,
                                          const float* W3, const float* as3, const float* ad3,
                                          unsigned short* Wa1, unsigned short* Wa2, unsigned short* Wa3,
                                          unsigned short* Wc1, unsigned short* Wc2, unsigned short* Wc3){
    if(id < X4){
        const float4 v = *(const float4*)&x[(size_t)id * 4];
        ushort4v o;
        o[0] = f2bf(v.x); o[1] = f2bf(v.y); o[2] = f2bf(v.z); o[3] = f2bf(v.w);
        *(ushort4v*)&xbf[(size_t)id * 4] = o;
        return;
    }
    id -= X4;
    if(id < 16 * 128){ emit_wa(W1, as1, ad1, Wa1, 128, 64, id); return; }
    id -= 16 * 128;
    if(id < 16 * 64){ emit_wa(W2, as2, ad2, Wa2, 64, 64, id); return; }
    id -= 16 * 64;
    if(id < 16 * 64){ emit_wa(W3, as3, ad3, Wa3, 64, 40, id); return; }
    id -= 16 * 64;
    if(id < 64 * 512){ emit_wc(W1, Wc1, 128, 64, id); return; }
    id -= 64 * 512;
    if(id < 64 * 256){ emit_wc(W2, Wc2, 64, 64, id); return; }
    id -= 64 * 256;
    if(id < 48 * 256){ emit_wc(W3, Wc3, 64, 40, id); }
}

// ---------------- shared phase bodies (used by mega + standalone fallback) ----------------

template<int K>
__device__ __forceinline__ void agemm_body(const unsigned short* __restrict__ A,
                                           const unsigned short* __restrict__ Wa,
                                           float* __restrict__ ea, float* __restrict__ ed,
                                           int M, int bm){
    const int lane = threadIdx.x & 63;
    const int wave = threadIdx.x >> 6;
    const int quad = lane >> 4;
    const int l16 = lane & 15;
    const int m = min(bm + wave * 16 + l16, M - 1);
    f32x4 acc = {0,0,0,0};
    #pragma unroll
    for(int k0 = 0; k0 < K; k0 += 32){
        const short8v a = *(const short8v*)&A[(size_t)m * K + k0 + quad * 8];
        const short8v b = *(const short8v*)&Wa[(size_t)l16 * K + k0 + quad * 8];
        acc = __builtin_amdgcn_mfma_f32_16x16x32_bf16(a, b, acc, 0, 0, 0);
    }
    if(l16 < 8){
        const int h = l16 & 3;
        float* dst = (l16 < 4) ? ea : ed;
        const int rbase = bm + wave * 16 + quad * 4;
        #pragma unroll
        for(int r = 0; r < 4; r++){
            const int row = rbase + r;
            if(row < M){
                const float v = acc[r];
                *(f32x2*)&dst[(size_t)row * 8 + 2 * h] = (f32x2){__expf(v), __expf(NEG_SLOPE * v)};
            }
        }
    }
}

// edge-parallel RAW gather for one node n (1 node per wave, barrier-free).
// ls/lw are this wave's private LDS slices.
template<int K>
__device__ __forceinline__ void gather_body(const unsigned short* __restrict__ X,
                                            const int* __restrict__ row_ptr,
                                            const int* __restrict__ col,
                                            const float* __restrict__ ea,
                                            const float* __restrict__ ed,
                                            unsigned short* __restrict__ g,
                                            int n, int* __restrict__ ls,
                                            float (* __restrict__ lw)[4]){
    const int lane = threadIdx.x & 63;
    const int rs = row_ptr[n], re = row_ptr[n + 1];
    const int T = re - rs + 1;                    // edges + virtual self loop
    const float4 edA = *(const float4*)&ed[(size_t)n * 8];
    const float4 edB = *(const float4*)&ed[(size_t)n * 8 + 4];

    f32x2 acc[4];
    #pragma unroll
    for(int h = 0; h < 4; h++) acc[h] = (f32x2){0.f, 0.f};
    float d0 = 0.f, d1 = 0.f, d2 = 0.f, d3 = 0.f;

    const int c2 = (K == 128) ? (lane * 2) : ((lane & 31) * 2);
    const int eo = lane >> 5;

    for(int base = 0; base < T; base += 64){
        const int ecnt = min(T - base, 64);
        if(lane < ecnt){
            const int e = rs + base + lane;
            const int s = (e < re) ? col[e] : n;  // e==re => self loop
            const float4 eaA = *(const float4*)&ea[(size_t)s * 8];
            const float4 eaB = *(const float4*)&ea[(size_t)s * 8 + 4];
            const float w0 = fmaxf(eaA.x * edA.x, eaA.y * edA.y);
            const float w1 = fmaxf(eaA.z * edA.z, eaA.w * edA.w);
            const float w2 = fmaxf(eaB.x * edB.x, eaB.y * edB.y);
            const float w3 = fmaxf(eaB.z * edB.z, eaB.w * edB.w);
            d0 += w0; d1 += w1; d2 += w2; d3 += w3;
            ls[lane] = s;
            *(f32x4*)&lw[lane][0] = (f32x4){w0, w1, w2, w3};
        }
        if constexpr(K == 128){
            auto body = [&](int e){
                const int s = ls[e];                            // LDS broadcast
                const f32x4 w4 = *(const f32x4*)&lw[e][0];
                const unsigned u = *(const unsigned*)&X[(size_t)s * K + c2];
                const f32x2 v = {__uint_as_float(u << 16), __uint_as_float(u & 0xffff0000u)};
                acc[0] += (f32x2){w4[0], w4[0]} * v;
                acc[1] += (f32x2){w4[1], w4[1]} * v;
                acc[2] += (f32x2){w4[2], w4[2]} * v;
                acc[3] += (f32x2){w4[3], w4[3]} * v;
            };
            int e = 0;
            for(; e + 4 <= ecnt; e += 4){ body(e); body(e + 1); body(e + 2); body(e + 3); }
            for(; e < ecnt; e++) body(e);
        } else {
            auto body = [&](int p){                             // pair: edges p, p+1
                const int e = p + eo;
                if(e < ecnt){
                    const int s = ls[e];                        // 2-way LDS (free)
                    const f32x4 w4 = *(const f32x4*)&lw[e][0];
                    const unsigned u = *(const unsigned*)&X[(size_t)s * K + c2];
                    const f32x2 v = {__uint_as_float(u << 16), __uint_as_float(u & 0xffff0000u)};
                    acc[0] += (f32x2){w4[0], w4[0]} * v;
                    acc[1] += (f32x2){w4[1], w4[1]} * v;
                    acc[2] += (f32x2){w4[2], w4[2]} * v;
                    acc[3] += (f32x2){w4[3], w4[3]} * v;
                }
            };
            int p = 0;
            for(; p + 8 <= ecnt; p += 8){ body(p); body(p + 2); body(p + 4); body(p + 6); }
            for(; p < ecnt; p += 2) body(p);
        }
    }

    #pragma unroll
    for(int msk = 1; msk < 64; msk <<= 1){
        d0 += __shfl_xor(d0, msk); d1 += __shfl_xor(d1, msk);
        d2 += __shfl_xor(d2, msk); d3 += __shfl_xor(d3, msk);
    }
    if constexpr(K == 64){
        #pragma unroll
        for(int h = 0; h < 4; h++){
            acc[h][0] += __shfl_xor(acc[h][0], 32);
            acc[h][1] += __shfl_xor(acc[h][1], 32);
        }
    }
    const float invs[4] = {1.f / d0, 1.f / d1, 1.f / d2, 1.f / d3};
    if(K == 128 || lane < 32){
        #pragma unroll
        for(int h = 0; h < 4; h++){
            const unsigned lo = f2bf(acc[h][0] * invs[h]);
            const unsigned hi = f2bf(acc[h][1] * invs[h]);
            *(unsigned*)&g[(size_t)n * (4 * K) + h * K + c2] = lo | (hi << 16);
        }
    }
}

// post-aggregation GEMM for one 64-row tile (bm). lh is this wave's [16][72] slice.
template<int KC, int NC, bool FINAL, bool ALPHA>
__device__ __forceinline__ void pgemm_body(const unsigned short* __restrict__ A,
                                           const unsigned short* __restrict__ Bt,
                                           const float* __restrict__ bias,
                                           void* __restrict__ outv,
                                           const unsigned short* __restrict__ Wa,
                                           float* __restrict__ ea, float* __restrict__ ed,
                                           int M, int bm,
                                           unsigned short (* __restrict__ lh)[72]){
    constexpr int NT = (NC + 15) / 16;
    const int lane = threadIdx.x & 63;
    const int quad = lane >> 4;
    const int l16 = lane & 15;
    const int m = min(bm + (threadIdx.x >> 6) * 0 + 0, 0) * 0 + min(bm + ((threadIdx.x >> 6) & 0) , M - 1); // placeholder avoided below
    (void)m;
    const int wrow = bm + l16;          // per-wave tile: each wave handles its own bm
    const int mm = min(wrow, M - 1);
    const size_t arow = (size_t)mm * KC;

    f32x4 acc[NT];
    #pragma unroll
    for(int t = 0; t < NT; t++) acc[t] = (f32x4){0,0,0,0};

    for(int k0 = 0; k0 < KC; k0 += 32){
        const short8v a = *(const short8v*)&A[arow + k0 + quad * 8];
        #pragma unroll
        for(int t = 0; t < NT; t++){
            const short8v b = *(const short8v*)&Bt[(size_t)(t * 16 + l16) * KC + k0 + quad * 8];
            acc[t] = __builtin_amdgcn_mfma_f32_16x16x32_bf16(a, b, acc[t], 0, 0, 0);
        }
    }
    const int rbase = bm + quad * 4;
    if constexpr(!FINAL){
        unsigned short* out = (unsigned short*)outv;
        #pragma unroll
        for(int t = 0; t < NT; t++){
            const int c = t * 16 + l16;
            #pragma unroll
            for(int r = 0; r < 4; r++){
                const unsigned short hb = f2bf(fmaxf(acc[t][r] + bias[c], 0.f));
                const int row = rbase + r;
                if(row < M) out[(size_t)row * NC + c] = hb;
                if constexpr(ALPHA) lh[quad * 4 + r][c] = hb;
            }
        }
        if constexpr(ALPHA){
            // wave-private LDS tile: within-wave lgkmcnt ordering suffices (no barrier)
            f32x4 a4 = {0, 0, 0, 0};
            #pragma unroll
            for(int k0 = 0; k0 < 64; k0 += 32){
                const short8v a = *(const short8v*)&lh[l16][k0 + quad * 8];
                const short8v b = *(const short8v*)&Wa[(size_t)l16 * 64 + k0 + quad * 8];
                a4 = __builtin_amdgcn_mfma_f32_16x16x32_bf16(a, b, a4, 0, 0, 0);
            }
            if(l16 < 8){
                const int h = l16 & 3;
                float* dst = (l16 < 4) ? ea : ed;
                #pragma unroll
                for(int r = 0; r < 4; r++){
                    const int row = rbase + r;
                    if(row < M){
                        const float v = a4[r];
                        *(f32x2*)&dst[(size_t)row * 8 + 2 * h] = (f32x2){__expf(v), __expf(NEG_SLOPE * v)};
                    }
                }
            }
        }
    } else {
        float* out = (float*)outv;
        float o[NT][4];
        #pragma unroll
        for(int t = 0; t < NT; t++){
            const int c = t * 16 + l16;
            const bool valid = c < 40;
            const float bc = valid ? bias[c] : 0.f;
            #pragma unroll
            for(int r = 0; r < 4; r++)
                o[t][r] = valid ? fmaxf(acc[t][r] + bc, 0.f) : -INFINITY;
        }
        #pragma unroll
        for(int r = 0; r < 4; r++){
            float mx = o[0][r];
            #pragma unroll
            for(int t = 1; t < NT; t++) mx = fmaxf(mx, o[t][r]);
            #pragma unroll
            for(int off = 1; off < 16; off <<= 1) mx = fmaxf(mx, __shfl_xor(mx, off));
            float se = 0.f;
            #pragma unroll
            for(int t = 0; t < NT; t++) se += (o[t][r] > -INFINITY) ? __expf(o[t][r] - mx) : 0.f;
            #pragma unroll
            for(int off = 1; off < 16; off <<= 1) se += __shfl_xor(se, off);
            const float lz = mx + logf(se);
            const int row = rbase + r;
            if(row < M){
                #pragma unroll
                for(int t = 0; t < NT; t++){
                    const int c = t * 16 + l16;
                    if(c < 40) out[(size_t)row * 40 + c] = o[t][r] - lz;
                }
            }
        }
    }
}

// per-bucket CSR finalize (contains block barriers; all 256 threads must enter)
__device__ __forceinline__ void bfinal_body(const unsigned* __restrict__ ebuf,
                                            const int* __restrict__ blkcnt,
                                            int* __restrict__ row_ptr, int* __restrict__ col,
                                            int N, int E, int nbin, int b,
                                            int* __restrict__ lcnt, int* __restrict__ lcur,
                                            int* __restrict__ sh){
    const int t = threadIdx.x;
    const int nlo = b << 7;
    const int base = blkcnt[b * nbin];
    const int next = (b == NBUCKET - 1) ? E : blkcnt[(b + 1) * nbin];
    const int cnt = next - base;
    if(t < 128) lcnt[t] = 0;
    __syncthreads();
    for(int i = t; i < cnt; i += 256) atomicAdd(&lcnt[(ebuf[base + i] >> 16) & 127], 1);
    __syncthreads();
    if(t < 128) sh[t] = lcnt[t];
    __syncthreads();
    for(int off = 1; off < 128; off <<= 1){
        const int add = (t >= off && t < 128) ? sh[t - off] : 0;
        __syncthreads();
        if(t < 128) sh[t] += add;
        __syncthreads();
    }
    if(t < 128){
        const int excl = sh[t] - lcnt[t];
        lcur[t] = excl;
        if(nlo + t < N) row_ptr[nlo + t] = base + excl;
    }
    __syncthreads();
    for(int i = t; i < cnt; i += 256){
        const unsigned w = ebuf[base + i];
        const int p = atomicAdd(&lcur[(w >> 16) & 127], 1);
        col[base + p] = (int)(w & 0xffffu);
    }
    __syncthreads();
}

// ==================== MEGA (cooperative) ====================
struct MegaArgs {
    const void* eraw; int E;
    int* flag;
    const float* x;
    const float* W1; const float* as1; const float* ad1; const float* b1;
    const float* W2; const float* as2; const float* ad2; const float* b2;
    const float* W3; const float* as3; const float* ad3; const float* b3;
    unsigned short* xbf;
    unsigned short* Wa1; unsigned short* Wa2; unsigned short* Wa3;
    unsigned short* Wc1; unsigned short* Wc2; unsigned short* Wc3;
    int* blkcnt; unsigned* ebuf; int* row_ptr; int* colv;
    float* eav; float* edv;
    unsigned short* g; unsigned short* h1; unsigned short* h2;
    void* out;
};

__global__ __launch_bounds__(256) void mega_kernel(MegaArgs a){
    union Smem {
        struct { int ls[4][64]; float lw[4][64][4]; } gat;   // gather: wave-private slices
        int hist[NBUCKET];                                   // bincount
        int cur[NBUCKET];                                    // binscatter cursors
        int part[256];                                       // binscan partials
        struct { int lcnt[128]; int lcur[128]; int sh[128]; } fin;
        unsigned short lh[4][16][72];                        // pgemm ALPHA tiles
    };
    __shared__ Smem sm;
    cg::grid_group grid = cg::this_grid();
    const int t = threadIdx.x;
    const int wave = t >> 6;
    const int NB = gridDim.x;
    const int E = a.E;
    const int mBlocks = (NNODES + 63) / 64;   // 782
    const int nGroups = NNODES / 4;           // 12500

    // ---- P0: flag detect + prep (xbf, Wa*, Wc*) ----
    if(blockIdx.x == 0 && t < 64){
        const unsigned long long v = ((const unsigned long long*)a.eraw)[t];
        const unsigned long long mask = __ballot(v >= (1ULL << 32));
        if(t == 0) *a.flag = (mask == 0ULL) ? 1 : 0;
    }
    {
        const int X4 = NNODES * 32;
        const int prepTotal = X4 + 16*128 + 16*64 + 16*64 + 64*512 + 64*256 + 48*256;
        for(int id = blockIdx.x * 256 + t; id < prepTotal; id += NB * 256)
            prep_item(id, a.x, a.xbf, X4, a.W1, a.as1, a.ad1, a.W2, a.as2, a.ad2,
                      a.W3, a.as3, a.ad3, a.Wa1, a.Wa2, a.Wa3, a.Wc1, a.Wc2, a.Wc3);
    }
    grid.sync();

    // ---- P1: bincount (blocks 0..63) || agemm layer-1 (remaining blocks) ----
    const int chunk = (E + 63) >> 6;
    if(blockIdx.x < 64){
        for(int i = t; i < NBUCKET; i += 256) sm.hist[i] = 0;
        __syncthreads();
        const bool f = (*a.flag) != 0;
        const int beg = blockIdx.x * chunk, end = min(beg + chunk, E);
        for(int i = beg + t; i < end; i += 256){
            const int d = f ? (int)((const long long*)a.eraw)[E + i] : ((const int*)a.eraw)[E + i];
            atomicAdd(&sm.hist[d >> 7], 1);
        }
        __syncthreads();
        for(int b = t; b < NBUCKET; b += 256) a.blkcnt[b * 64 + blockIdx.x] = sm.hist[b];
    } else {
        for(int mb = blockIdx.x - 64; mb < mBlocks; mb += NB - 64)
            agemm_body<128>(a.xbf, a.Wa1, a.eav, a.edv, NNODES, mb * 64);
    }
    grid.sync();

    // ---- P2: scan of blkcnt[391*64] (block 0) ----
    if(blockIdx.x == 0){
        const int total = NBUCKET * 64;
        const int per = (total + 255) / 256;
        const int beg = t * per, end = min(beg + per, total);
        int sum = 0;
        for(int i = beg; i < end; i++) sum += a.blkcnt[i];
        sm.part[t] = sum;
        __syncthreads();
        for(int off = 1; off < 256; off <<= 1){
            const int add = (t >= off) ? sm.part[t - off] : 0;
            __syncthreads();
            sm.part[t] += add;
            __syncthreads();
        }
        int run = sm.part[t] - sum;
        for(int i = beg; i < end; i++){
            const int v = a.blkcnt[i];
            a.blkcnt[i] = run;
            run += v;
        }
    }
    grid.sync();

    // ---- P3: binscatter, direct-write with LDS cursors (blocks 0..63) ----
    if(blockIdx.x < 64){
        for(int b = t; b < NBUCKET; b += 256) sm.cur[b] = a.blkcnt[b * 64 + blockIdx.x];
        __syncthreads();
        const bool f = (*a.flag) != 0;
        const int beg = blockIdx.x * chunk, end = min(beg + chunk, E);
        for(int i = beg + t; i < end; i += 256){
            int s, d;
            if(f){ s = (int)((const long long*)a.eraw)[i]; d = (int)((const long long*)a.eraw)[E + i]; }
            else { s = ((const int*)a.eraw)[i];            d = ((const int*)a.eraw)[E + i]; }
            const int b = d >> 7;
            const int p = atomicAdd(&sm.cur[b], 1);
            a.ebuf[p] = (unsigned)s | ((unsigned)(d & 127) << 16) | ((unsigned)b << 23);
        }
    }
    grid.sync();

    // ---- P4: per-bucket finalize -> row_ptr, col ----
    if(blockIdx.x == 0 && t == 0) a.row_ptr[NNODES] = E;
    for(int b = blockIdx.x; b < NBUCKET; b += NB)
        bfinal_body(a.ebuf, a.blkcnt, a.row_ptr, a.colv, NNODES, E, 64, b,
                    sm.fin.lcnt, sm.fin.lcur, sm.fin.sh);
    grid.sync();

    // ---- P5: gather layer 1 (raw x, K=128) ----
    for(int grp = blockIdx.x; grp < nGroups; grp += NB)
        gather_body<128>(a.xbf, a.row_ptr, a.colv, a.eav, a.edv, a.g,
                         grp * 4 + wave, sm.gat.ls[wave], sm.gat.lw[wave]);
    grid.sync();

    // ---- P6: pgemm1 (+alpha layer 2) ----
    for(int mb = blockIdx.x; mb < mBlocks; mb += NB)
        pgemm_body<512, 64, false, true>(a.g, a.Wc1, a.b1, a.h1, a.Wa2, a.eav, a.edv,
                                         NNODES, mb * 64 + wave * 16, sm.lh[wave]);
    grid.sync();

    // ---- P7: gather layer 2 (h1, K=64) ----
    for(int grp = blockIdx.x; grp < nGroups; grp += NB)
        gather_body<64>(a.h1, a.row_ptr, a.colv, a.eav, a.edv, a.g,
                        grp * 4 + wave, sm.gat.ls[wave], sm.gat.lw[wave]);
    grid.sync();

    // ---- P8: pgemm2 (+alpha layer 3) ----
    for(int mb = blockIdx.x; mb < mBlocks; mb += NB)
        pgemm_body<256, 64, false, true>(a.g, a.Wc2, a.b2, a.h2, a.Wa3, a.eav, a.edv,
                                         NNODES, mb * 64 + wave * 16, sm.lh[wave]);
    grid.sync();

    // ---- P9: gather layer 3 (h2, K=64) ----
    for(int grp = blockIdx.x; grp < nGroups; grp += NB)
        gather_body<64>(a.h2, a.row_ptr, a.colv, a.eav, a.edv, a.g,
                        grp * 4 + wave, sm.gat.ls[wave], sm.gat.lw[wave]);
    grid.sync();

    // ---- P10: pgemm3 + log_softmax ----
    for(int mb = blockIdx.x; mb < mBlocks; mb += NB)
        pgemm_body<256, 40, true, false>(a.g, a.Wc3, a.b3, a.out, nullptr, nullptr, nullptr,
                                         NNODES, mb * 64 + wave * 16, sm.lh[wave]);
}

// ==================== standalone fallback kernels (round-6 path) ====================

__global__ void initprep_kernel(const unsigned long long* __restrict__ e, int* __restrict__ flag,
                                const float* __restrict__ x, unsigned short* __restrict__ xbf, int X4,
                                const float* __restrict__ W1, const float* __restrict__ as1, const float* __restrict__ ad1,
                                const float* __restrict__ W2, const float* __restrict__ as2, const float* __restrict__ ad2,
                                const float* __restrict__ W3, const float* __restrict__ as3, const float* __restrict__ ad3,
                                unsigned short* __restrict__ Wa1, unsigned short* __restrict__ Wa2,
                                unsigned short* __restrict__ Wa3, unsigned short* __restrict__ Wc1,
                                unsigned short* __restrict__ Wc2, unsigned short* __restrict__ Wc3){
    if(blockIdx.x == 0 && threadIdx.x < 64){
        const unsigned long long v = e[threadIdx.x];
        const unsigned long long mask = __ballot(v >= (1ULL << 32));
        if(threadIdx.x == 0) *flag = (mask == 0ULL) ? 1 : 0;
    }
    const int id = blockIdx.x * blockDim.x + threadIdx.x;
    prep_item(id, x, xbf, X4, W1, as1, ad1, W2, as2, ad2, W3, as3, ad3,
              Wa1, Wa2, Wa3, Wc1, Wc2, Wc3);
}

__global__ __launch_bounds__(256) void bincount_kernel(const void* __restrict__ e, const int* __restrict__ flag,
                                                       int* __restrict__ blkcnt, int E, int nbin, int chunk){
    __shared__ int lcnt[NBUCKET];
    for(int i = threadIdx.x; i < NBUCKET; i += 256) lcnt[i] = 0;
    __syncthreads();
    const bool f = (*flag) != 0;
    const int beg = blockIdx.x * chunk;
    const int end = min(beg + chunk, E);
    for(int i = beg + threadIdx.x; i < end; i += 256){
        const int d = f ? (int)((const long long*)e)[E + i] : ((const int*)e)[E + i];
        atomicAdd(&lcnt[d >> 7], 1);
    }
    __syncthreads();
    for(int b = threadIdx.x; b < NBUCKET; b += 256)
        blkcnt[b * nbin + blockIdx.x] = lcnt[b];
}

__global__ __launch_bounds__(256) void binscan_kernel(int* __restrict__ blkcnt, int total){
    __shared__ int part[256];
    const int t = threadIdx.x;
    const int per = (total + 255) / 256;
    const int beg = t * per, end = min(beg + per, total);
    int sum = 0;
    for(int i = beg; i < end; i++) sum += blkcnt[i];
    part[t] = sum;
    __syncthreads();
    for(int off = 1; off < 256; off <<= 1){
        const int add = (t >= off) ? part[t - off] : 0;
        __syncthreads();
        part[t] += add;
        __syncthreads();
    }
    int run = part[t] - sum;
    for(int i = beg; i < end; i++){
        const int v = blkcnt[i];
        blkcnt[i] = run;
        run += v;
    }
}

__global__ __launch_bounds__(256) void binscatter_kernel(const void* __restrict__ e, const int* __restrict__ flag,
                                                         const int* __restrict__ blkcnt,
                                                         unsigned* __restrict__ ebuf,
                                                         int E, int nbin, int chunk){
    __shared__ int lcur[NBUCKET];
    const int t = threadIdx.x;
    for(int b = t; b < NBUCKET; b += 256) lcur[b] = blkcnt[b * nbin + blockIdx.x];
    __syncthreads();
    const bool f = (*flag) != 0;
    const int beg = blockIdx.x * chunk;
    const int end = min(beg + chunk, E);
    for(int i = beg + t; i < end; i += 256){
        int s, d;
        if(f){ s = (int)((const long long*)e)[i]; d = (int)((const long long*)e)[E + i]; }
        else { s = ((const int*)e)[i];            d = ((const int*)e)[E + i]; }
        const int b = d >> 7;
        const int p = atomicAdd(&lcur[b], 1);
        ebuf[p] = (unsigned)s | ((unsigned)(d & 127) << 16) | ((unsigned)b << 23);
    }
}

__global__ __launch_bounds__(256) void bfinal_kernel(const unsigned* __restrict__ ebuf,
                                                     const int* __restrict__ blkcnt,
                                                     int* __restrict__ row_ptr, int* __restrict__ col,
                                                     int N, int E, int nbin){
    __shared__ int lcnt[128], lcur[128], sh[128];
    if(blockIdx.x == 0 && threadIdx.x == 0) row_ptr[N] = E;
    bfinal_body(ebuf, blkcnt, row_ptr, col, N, E, nbin, blockIdx.x, lcnt, lcur, sh);
}

template<int K>
__global__ __launch_bounds__(256) void agemm_kernel(const unsigned short* __restrict__ A,
                                                    const unsigned short* __restrict__ Wa,
                                                    float* __restrict__ ea, float* __restrict__ ed,
                                                    int M){
    agemm_body<K>(A, Wa, ea, ed, M, blockIdx.x * 64);
}

template<int K>
__global__ __launch_bounds__(256) void gatherg_kernel(const unsigned short* __restrict__ X,
                                                      const int* __restrict__ row_ptr,
                                                      const int* __restrict__ col,
                                                      const float* __restrict__ ea,
                                                      const float* __restrict__ ed,
                                                      unsigned short* __restrict__ g){
    __shared__ int   ls[4][64];
    __shared__ float lw[4][64][4];
    const int wave = threadIdx.x >> 6;
    gather_body<K>(X, row_ptr, col, ea, ed, g, blockIdx.x * 4 + wave, ls[wave], lw[wave]);
}

template<int KC, int NC, bool FINAL, bool ALPHA>
__global__ __launch_bounds__(256) void pgemm_kernel(const unsigned short* __restrict__ A,
                                                    const unsigned short* __restrict__ Bt,
                                                    const float* __restrict__ bias,
                                                    void* __restrict__ outv,
                                                    const unsigned short* __restrict__ Wa,
                                                    float* __restrict__ ea,
                                                    float* __restrict__ ed,
                                                    int M){
    __shared__ unsigned short lh[ALPHA ? 4 : 1][16][72];
    const int wave = threadIdx.x >> 6;
    pgemm_body<KC, NC, FINAL, ALPHA>(A, Bt, bias, outv, Wa, ea, ed, M,
                                     blockIdx.x * 64 + wave * 16,
                                     lh[ALPHA ? wave : 0]);
}

// ---------------- driver ----------------
extern "C" void kernel_launch(void* const* d_in, const int* in_sizes, int n_in,
                              void* d_out, int out_size, void* d_ws, size_t ws_size,
                              hipStream_t stream){
    const int N = NNODES;
    const int E = in_sizes[1] / 2;

    const float* x   = (const float*)d_in[0];
    const float* W1  = (const float*)d_in[2];
    const float* as1 = (const float*)d_in[3];
    const float* ad1 = (const float*)d_in[4];
    const float* b1  = (const float*)d_in[5];
    const float* W2  = (const float*)d_in[6];
    const float* as2 = (const float*)d_in[7];
    const float* ad2 = (const float*)d_in[8];
    const float* b2  = (const float*)d_in[9];
    const float* W3  = (const float*)d_in[10];
    const float* as3 = (const float*)d_in[11];
    const float* ad3 = (const float*)d_in[12];
    const float* b3  = (const float*)d_in[13];

    char* ws = (char*)d_ws;
    size_t off = 0;
    auto alloc = [&](size_t bytes) -> void* {
        void* p = ws + off;
        off = (off + bytes + 255) & ~(size_t)255;
        return p;
    };
    int*      flag    = (int*)     alloc(4);
    int*      row_ptr = (int*)     alloc((size_t)(N + 1) * 4);
    int*      colv    = (int*)     alloc((size_t)E * 4);
    int*      blkcnt  = (int*)     alloc((size_t)NBUCKET * NBIN_MAX * 4);
    unsigned* ebuf    = (unsigned*)alloc((size_t)E * 4);
    unsigned short* xbf = (unsigned short*)alloc((size_t)N * 128 * 2);
    unsigned short* Wa1 = (unsigned short*)alloc(16 * 128 * 2);
    unsigned short* Wa2 = (unsigned short*)alloc(16 * 64 * 2);
    unsigned short* Wa3 = (unsigned short*)alloc(16 * 64 * 2);
    unsigned short* Wc1 = (unsigned short*)alloc((size_t)64 * 512 * 2);
    unsigned short* Wc2 = (unsigned short*)alloc((size_t)64 * 256 * 2);
    unsigned short* Wc3 = (unsigned short*)alloc((size_t)48 * 256 * 2);
    float* eav     = (float*)alloc((size_t)N * 8 * 4);
    float* edv     = (float*)alloc((size_t)N * 8 * 4);
    unsigned short* g   = (unsigned short*)alloc((size_t)N * 512 * 2);
    unsigned short* h1  = (unsigned short*)alloc((size_t)N * 64 * 2);
    unsigned short* h2  = (unsigned short*)alloc((size_t)N * 64 * 2);
    (void)ws_size;

    const void* eraw = d_in[1];

    // ---- try the cooperative mega-kernel ----
    bool launched = false;
    int dev = 0;
    (void)hipGetDevice(&dev);
    int coop = 0;
    (void)hipDeviceGetAttribute(&coop, hipDeviceAttributeCooperativeLaunch, dev);
    if(coop){
        int maxPerCU = 0;
        if(hipOccupancyMaxActiveBlocksPerMultiprocessor(&maxPerCU, mega_kernel, 256, 0) == hipSuccess
           && maxPerCU > 0){
            int numCU = 0;
            (void)hipDeviceGetAttribute(&numCU, hipDeviceAttributeMultiprocessorCount, dev);
            const int nblk = maxPerCU * numCU;
            if(nblk >= 320){
                MegaArgs ma;
                ma.eraw = eraw; ma.E = E; ma.flag = flag; ma.x = x;
                ma.W1 = W1; ma.as1 = as1; ma.ad1 = ad1; ma.b1 = b1;
                ma.W2 = W2; ma.as2 = as2; ma.ad2 = ad2; ma.b2 = b2;
                ma.W3 = W3; ma.as3 = as3; ma.ad3 = ad3; ma.b3 = b3;
                ma.xbf = xbf; ma.Wa1 = Wa1; ma.Wa2 = Wa2; ma.Wa3 = Wa3;
                ma.Wc1 = Wc1; ma.Wc2 = Wc2; ma.Wc3 = Wc3;
                ma.blkcnt = blkcnt; ma.ebuf = ebuf; ma.row_ptr = row_ptr; ma.colv = colv;
                ma.eav = eav; ma.edv = edv; ma.g = g; ma.h1 = h1; ma.h2 = h2;
                ma.out = d_out;
                void* kargs[] = { (void*)&ma };
                if(hipLaunchCooperativeKernel(mega_kernel, dim3(nblk), dim3(256),
                                              kargs, 0, stream) == hipSuccess){
                    launched = true;
                } else {
                    (void)hipGetLastError();   // clear sticky error, fall through
                }
            }
        }
    }
    if(launched) return;

    // ---- fallback: proven round-6 multi-kernel path ----
    const int X4 = N * 128 / 4;
    const int prepTotal = X4 + 16*128 + 16*64 + 16*64 + 64*512 + 64*256 + 48*256;
    initprep_kernel<<<(prepTotal + 255) / 256, 256, 0, stream>>>(
        (const unsigned long long*)eraw, flag, x, xbf, X4,
        W1, as1, ad1, W2, as2, ad2, W3, as3, ad3,
        Wa1, Wa2, Wa3, Wc1, Wc2, Wc3);

    const int nbin = 64;
    const int chunkE = (E + nbin - 1) / nbin;
    bincount_kernel<<<nbin, 256, 0, stream>>>(eraw, flag, blkcnt, E, nbin, chunkE);
    binscan_kernel<<<1, 256, 0, stream>>>(blkcnt, NBUCKET * nbin);
    binscatter_kernel<<<nbin, 256, 0, stream>>>(eraw, flag, blkcnt, ebuf, E, nbin, chunkE);
    bfinal_kernel<<<NBUCKET, 256, 0, stream>>>(ebuf, blkcnt, row_ptr, colv, N, E, nbin);

    const int nodeBlocks = N / 4;              // 12500
    const int mBlocks = (N + 63) / 64;         // 782

    agemm_kernel<128><<<mBlocks, 256, 0, stream>>>(xbf, Wa1, eav, edv, N);
    gatherg_kernel<128><<<nodeBlocks, 256, 0, stream>>>(xbf, row_ptr, colv, eav, edv, g);
    pgemm_kernel<512, 64, false, true><<<mBlocks, 256, 0, stream>>>(g, Wc1, b1, h1, Wa2, eav, edv, N);

    gatherg_kernel<64><<<nodeBlocks, 256, 0, stream>>>(h1, row_ptr, colv, eav, edv, g);
    pgemm_kernel<256, 64, false, true><<<mBlocks, 256, 0, stream>>>(g, Wc2, b2, h2, Wa3, eav, edv, N);

    gatherg_kernel<64><<<nodeBlocks, 256, 0, stream>>>(h2, row_ptr, colv, eav, edv, g);
    pgemm_kernel<256, 40, true, false><<<mBlocks, 256, 0, stream>>>(g, Wc3, b3, d_out, nullptr, nullptr, nullptr, N);
}

// Round 8
// 413.073 us; speedup vs baseline: 1.0209x; 1.0209x over previous
//
#include <hip/hip_runtime.h>
#include <math.h>

#define NNODES 50000
#define NEG_SLOPE 0.2f
#define NBUCKET 391          // buckets of 128 nodes; s fits 16 bits (N < 65536)
#define NBIN_MAX 128
#define NBAR 10              // grid barriers in the mega kernel
#define MAXB 2048            // max persistent blocks

typedef unsigned short ushort8v __attribute__((ext_vector_type(8)));
typedef unsigned short ushort4v __attribute__((ext_vector_type(4)));
typedef short short8v __attribute__((ext_vector_type(8)));
typedef float f32x4 __attribute__((ext_vector_type(4)));
typedef float f32x2 __attribute__((ext_vector_type(2)));

__device__ __forceinline__ unsigned short f2bf(float f){
    unsigned u = __float_as_uint(f);
    u += 0x7fff + ((u >> 16) & 1);   // RNE; inputs finite
    return (unsigned short)(u >> 16);
}

// ---------------- prep helpers ----------------
__device__ __forceinline__ void emit_wa(const float* __restrict__ W, const float* __restrict__ a_s,
                                        const float* __restrict__ a_d, unsigned short* __restrict__ Wt,
                                        int Kin, int C, int id){
    const int n = id / Kin, k = id - n * Kin;
    float v = 0.f;
    if(n < 8){
        const int hh = n & 3;
        const float* av = (n < 4) ? a_s : a_d;
        for(int c = 0; c < C; c++) v += W[(size_t)k * (4 * C) + hh * C + c] * av[hh * C + c];
    }
    Wt[id] = f2bf(v);
}

__device__ __forceinline__ void emit_wc(const float* __restrict__ W, unsigned short* __restrict__ Wt,
                                        int Kin, int C, int id){
    const int c = id / (4 * Kin);
    const int hk = id - c * (4 * Kin);
    const int h = hk / Kin, k = hk - h * Kin;
    const float v = (c < C) ? W[(size_t)k * (4 * C) + h * C + c] * 0.25f : 0.f;
    Wt[id] = f2bf(v);
}

__device__ __forceinline__ void prep_item(int id, const float* __restrict__ x,
                                          unsigned short* __restrict__ xbf, int X4,
                                          const float* W1, const float* as1, const float* ad1,
                                          const float* W2, const float* as2, const float* ad2,
                                          const float* W3, const float* as3, const float* ad3,
                                          unsigned short* Wa1, unsigned short* Wa2, unsigned short* Wa3,
                                          unsigned short* Wc1, unsigned short* Wc2, unsigned short* Wc3){
    if(id < X4){
        const float4 v = *(const float4*)&x[(size_t)id * 4];
        ushort4v o;
        o[0] = f2bf(v.x); o[1] = f2bf(v.y); o[2] = f2bf(v.z); o[3] = f2bf(v.w);
        *(ushort4v*)&xbf[(size_t)id * 4] = o;
        return;
    }
    id -= X4;
    if(id < 16 * 128){ emit_wa(W1, as1, ad1, Wa1, 128, 64, id); return; }
    id -= 16 * 128;
    if(id < 16 * 64){ emit_wa(W2, as2, ad2, Wa2, 64, 64, id); return; }
    id -= 16 * 64;
    if(id < 16 * 64){ emit_wa(W3, as3, ad3, Wa3, 64, 40, id); return; }
    id -= 16 * 64;
    if(id < 64 * 512){ emit_wc(W1, Wc1, 128, 64, id); return; }
    id -= 64 * 512;
    if(id < 64 * 256){ emit_wc(W2, Wc2, 64, 64, id); return; }
    id -= 64 * 256;
    if(id < 48 * 256){ emit_wc(W3, Wc3, 64, 40, id); }
}

// ---------------- shared phase bodies ----------------

template<int K>
__device__ __forceinline__ void agemm_body(const unsigned short* __restrict__ A,
                                           const unsigned short* __restrict__ Wa,
                                           float* __restrict__ ea, float* __restrict__ ed,
                                           int M, int bm){
    const int lane = threadIdx.x & 63;
    const int wave = threadIdx.x >> 6;
    const int quad = lane >> 4;
    const int l16 = lane & 15;
    const int m = min(bm + wave * 16 + l16, M - 1);
    f32x4 acc = {0,0,0,0};
    #pragma unroll
    for(int k0 = 0; k0 < K; k0 += 32){
        const short8v a = *(const short8v*)&A[(size_t)m * K + k0 + quad * 8];
        const short8v b = *(const short8v*)&Wa[(size_t)l16 * K + k0 + quad * 8];
        acc = __builtin_amdgcn_mfma_f32_16x16x32_bf16(a, b, acc, 0, 0, 0);
    }
    if(l16 < 8){
        const int h = l16 & 3;
        float* dst = (l16 < 4) ? ea : ed;
        const int rbase = bm + wave * 16 + quad * 4;
        #pragma unroll
        for(int r = 0; r < 4; r++){
            const int row = rbase + r;
            if(row < M){
                const float v = acc[r];
                *(f32x2*)&dst[(size_t)row * 8 + 2 * h] = (f32x2){__expf(v), __expf(NEG_SLOPE * v)};
            }
        }
    }
}

// edge-parallel RAW gather for one node n (1 node per wave, barrier-free).
template<int K>
__device__ __forceinline__ void gather_body(const unsigned short* __restrict__ X,
                                            const int* __restrict__ row_ptr,
                                            const int* __restrict__ col,
                                            const float* __restrict__ ea,
                                            const float* __restrict__ ed,
                                            unsigned short* __restrict__ g,
                                            int n, int* __restrict__ ls,
                                            float (* __restrict__ lw)[4]){
    const int lane = threadIdx.x & 63;
    const int rs = row_ptr[n], re = row_ptr[n + 1];
    const int T = re - rs + 1;                    // edges + virtual self loop
    const float4 edA = *(const float4*)&ed[(size_t)n * 8];
    const float4 edB = *(const float4*)&ed[(size_t)n * 8 + 4];

    f32x2 acc[4];
    #pragma unroll
    for(int h = 0; h < 4; h++) acc[h] = (f32x2){0.f, 0.f};
    float d0 = 0.f, d1 = 0.f, d2 = 0.f, d3 = 0.f;

    const int c2 = (K == 128) ? (lane * 2) : ((lane & 31) * 2);
    const int eo = lane >> 5;

    for(int base = 0; base < T; base += 64){
        const int ecnt = min(T - base, 64);
        if(lane < ecnt){
            const int e = rs + base + lane;
            const int s = (e < re) ? col[e] : n;  // e==re => self loop
            const float4 eaA = *(const float4*)&ea[(size_t)s * 8];
            const float4 eaB = *(const float4*)&ea[(size_t)s * 8 + 4];
            const float w0 = fmaxf(eaA.x * edA.x, eaA.y * edA.y);
            const float w1 = fmaxf(eaA.z * edA.z, eaA.w * edA.w);
            const float w2 = fmaxf(eaB.x * edB.x, eaB.y * edB.y);
            const float w3 = fmaxf(eaB.z * edB.z, eaB.w * edB.w);
            d0 += w0; d1 += w1; d2 += w2; d3 += w3;
            ls[lane] = s;
            *(f32x4*)&lw[lane][0] = (f32x4){w0, w1, w2, w3};
        }
        if constexpr(K == 128){
            auto body = [&](int e){
                const int s = ls[e];                            // LDS broadcast
                const f32x4 w4 = *(const f32x4*)&lw[e][0];
                const unsigned u = *(const unsigned*)&X[(size_t)s * K + c2];
                const f32x2 v = {__uint_as_float(u << 16), __uint_as_float(u & 0xffff0000u)};
                acc[0] += (f32x2){w4[0], w4[0]} * v;
                acc[1] += (f32x2){w4[1], w4[1]} * v;
                acc[2] += (f32x2){w4[2], w4[2]} * v;
                acc[3] += (f32x2){w4[3], w4[3]} * v;
            };
            int e = 0;
            for(; e + 4 <= ecnt; e += 4){ body(e); body(e + 1); body(e + 2); body(e + 3); }
            for(; e < ecnt; e++) body(e);
        } else {
            auto body = [&](int p){                             // pair: edges p, p+1
                const int e = p + eo;
                if(e < ecnt){
                    const int s = ls[e];                        // 2-way LDS (free)
                    const f32x4 w4 = *(const f32x4*)&lw[e][0];
                    const unsigned u = *(const unsigned*)&X[(size_t)s * K + c2];
                    const f32x2 v = {__uint_as_float(u << 16), __uint_as_float(u & 0xffff0000u)};
                    acc[0] += (f32x2){w4[0], w4[0]} * v;
                    acc[1] += (f32x2){w4[1], w4[1]} * v;
                    acc[2] += (f32x2){w4[2], w4[2]} * v;
                    acc[3] += (f32x2){w4[3], w4[3]} * v;
                }
            };
            int p = 0;
            for(; p + 8 <= ecnt; p += 8){ body(p); body(p + 2); body(p + 4); body(p + 6); }
            for(; p < ecnt; p += 2) body(p);
        }
    }

    #pragma unroll
    for(int msk = 1; msk < 64; msk <<= 1){
        d0 += __shfl_xor(d0, msk); d1 += __shfl_xor(d1, msk);
        d2 += __shfl_xor(d2, msk); d3 += __shfl_xor(d3, msk);
    }
    if constexpr(K == 64){
        #pragma unroll
        for(int h = 0; h < 4; h++){
            acc[h][0] += __shfl_xor(acc[h][0], 32);
            acc[h][1] += __shfl_xor(acc[h][1], 32);
        }
    }
    const float invs[4] = {1.f / d0, 1.f / d1, 1.f / d2, 1.f / d3};
    if(K == 128 || lane < 32){
        #pragma unroll
        for(int h = 0; h < 4; h++){
            const unsigned lo = f2bf(acc[h][0] * invs[h]);
            const unsigned hi = f2bf(acc[h][1] * invs[h]);
            *(unsigned*)&g[(size_t)n * (4 * K) + h * K + c2] = lo | (hi << 16);
        }
    }
}

// post-aggregation GEMM for one 16-row wave tile (bm). lh = wave's [16][72] slice.
template<int KC, int NC, bool FINAL, bool ALPHA>
__device__ __forceinline__ void pgemm_body(const unsigned short* __restrict__ A,
                                           const unsigned short* __restrict__ Bt,
                                           const float* __restrict__ bias,
                                           void* __restrict__ outv,
                                           const unsigned short* __restrict__ Wa,
                                           float* __restrict__ ea, float* __restrict__ ed,
                                           int M, int bm,
                                           unsigned short (* __restrict__ lh)[72]){
    constexpr int NT = (NC + 15) / 16;
    const int lane = threadIdx.x & 63;
    const int quad = lane >> 4;
    const int l16 = lane & 15;
    const int mm = min(bm + l16, M - 1);
    const size_t arow = (size_t)mm * KC;

    f32x4 acc[NT];
    #pragma unroll
    for(int t = 0; t < NT; t++) acc[t] = (f32x4){0,0,0,0};

    for(int k0 = 0; k0 < KC; k0 += 32){
        const short8v a = *(const short8v*)&A[arow + k0 + quad * 8];
        #pragma unroll
        for(int t = 0; t < NT; t++){
            const short8v b = *(const short8v*)&Bt[(size_t)(t * 16 + l16) * KC + k0 + quad * 8];
            acc[t] = __builtin_amdgcn_mfma_f32_16x16x32_bf16(a, b, acc[t], 0, 0, 0);
        }
    }
    const int rbase = bm + quad * 4;
    if constexpr(!FINAL){
        unsigned short* out = (unsigned short*)outv;
        #pragma unroll
        for(int t = 0; t < NT; t++){
            const int c = t * 16 + l16;
            #pragma unroll
            for(int r = 0; r < 4; r++){
                const unsigned short hb = f2bf(fmaxf(acc[t][r] + bias[c], 0.f));
                const int row = rbase + r;
                if(row < M) out[(size_t)row * NC + c] = hb;
                if constexpr(ALPHA) lh[quad * 4 + r][c] = hb;
            }
        }
        if constexpr(ALPHA){
            // wave-private LDS tile: within-wave lgkmcnt ordering suffices (no barrier)
            f32x4 a4 = {0, 0, 0, 0};
            #pragma unroll
            for(int k0 = 0; k0 < 64; k0 += 32){
                const short8v a = *(const short8v*)&lh[l16][k0 + quad * 8];
                const short8v b = *(const short8v*)&Wa[(size_t)l16 * 64 + k0 + quad * 8];
                a4 = __builtin_amdgcn_mfma_f32_16x16x32_bf16(a, b, a4, 0, 0, 0);
            }
            if(l16 < 8){
                const int h = l16 & 3;
                float* dst = (l16 < 4) ? ea : ed;
                #pragma unroll
                for(int r = 0; r < 4; r++){
                    const int row = rbase + r;
                    if(row < M){
                        const float v = a4[r];
                        *(f32x2*)&dst[(size_t)row * 8 + 2 * h] = (f32x2){__expf(v), __expf(NEG_SLOPE * v)};
                    }
                }
            }
        }
    } else {
        float* out = (float*)outv;
        float o[NT][4];
        #pragma unroll
        for(int t = 0; t < NT; t++){
            const int c = t * 16 + l16;
            const bool valid = c < 40;
            const float bc = valid ? bias[c] : 0.f;
            #pragma unroll
            for(int r = 0; r < 4; r++)
                o[t][r] = valid ? fmaxf(acc[t][r] + bc, 0.f) : -INFINITY;
        }
        #pragma unroll
        for(int r = 0; r < 4; r++){
            float mx = o[0][r];
            #pragma unroll
            for(int t = 1; t < NT; t++) mx = fmaxf(mx, o[t][r]);
            #pragma unroll
            for(int off = 1; off < 16; off <<= 1) mx = fmaxf(mx, __shfl_xor(mx, off));
            float se = 0.f;
            #pragma unroll
            for(int t = 0; t < NT; t++) se += (o[t][r] > -INFINITY) ? __expf(o[t][r] - mx) : 0.f;
            #pragma unroll
            for(int off = 1; off < 16; off <<= 1) se += __shfl_xor(se, off);
            const float lz = mx + logf(se);
            const int row = rbase + r;
            if(row < M){
                #pragma unroll
                for(int t = 0; t < NT; t++){
                    const int c = t * 16 + l16;
                    if(c < 40) out[(size_t)row * 40 + c] = o[t][r] - lz;
                }
            }
        }
    }
}

// per-bucket CSR finalize (contains block barriers; all 256 threads must enter)
__device__ __forceinline__ void bfinal_body(const unsigned* __restrict__ ebuf,
                                            const int* __restrict__ blkcnt,
                                            int* __restrict__ row_ptr, int* __restrict__ col,
                                            int N, int E, int nbin, int b,
                                            int* __restrict__ lcnt, int* __restrict__ lcur,
                                            int* __restrict__ sh){
    const int t = threadIdx.x;
    const int nlo = b << 7;
    const int base = blkcnt[b * nbin];
    const int next = (b == NBUCKET - 1) ? E : blkcnt[(b + 1) * nbin];
    const int cnt = next - base;
    if(t < 128) lcnt[t] = 0;
    __syncthreads();
    for(int i = t; i < cnt; i += 256) atomicAdd(&lcnt[(ebuf[base + i] >> 16) & 127], 1);
    __syncthreads();
    if(t < 128) sh[t] = lcnt[t];
    __syncthreads();
    for(int off = 1; off < 128; off <<= 1){
        const int add = (t >= off && t < 128) ? sh[t - off] : 0;
        __syncthreads();
        if(t < 128) sh[t] += add;
        __syncthreads();
    }
    if(t < 128){
        const int excl = sh[t] - lcnt[t];
        lcur[t] = excl;
        if(nlo + t < N) row_ptr[nlo + t] = base + excl;
    }
    __syncthreads();
    for(int i = t; i < cnt; i += 256){
        const unsigned w = ebuf[base + i];
        const int p = atomicAdd(&lcur[(w >> 16) & 127], 1);
        col[base + p] = (int)(w & 0xffffu);
    }
    __syncthreads();
}

// ---------------- software grid barrier (graph-capturable) ----------------
// slots[k][i]: block i's arrival for barrier k (release store); block 0 polls all
// slots then release-stores flags[k]; others acquire-spin on flags[k].
// State is zeroed by zbar_kernel in stream order before every mega launch.
__device__ __forceinline__ void gbar(unsigned* __restrict__ slots, unsigned* __restrict__ flags,
                                     int k, int nblk){
    __syncthreads();
    if(blockIdx.x == 0){
        unsigned* s = slots + (size_t)k * MAXB;
        for(int i = 1 + (int)threadIdx.x; i < nblk; i += 256){
            while(__hip_atomic_load(&s[i], __ATOMIC_ACQUIRE, __HIP_MEMORY_SCOPE_AGENT) == 0u)
                __builtin_amdgcn_s_sleep(8);
        }
        __syncthreads();
        if(threadIdx.x == 0)
            __hip_atomic_store(&flags[k], 1u, __ATOMIC_RELEASE, __HIP_MEMORY_SCOPE_AGENT);
    } else {
        if(threadIdx.x == 0){
            __hip_atomic_store(&slots[(size_t)k * MAXB + blockIdx.x], 1u,
                               __ATOMIC_RELEASE, __HIP_MEMORY_SCOPE_AGENT);
            while(__hip_atomic_load(&flags[k], __ATOMIC_ACQUIRE, __HIP_MEMORY_SCOPE_AGENT) == 0u)
                __builtin_amdgcn_s_sleep(8);
        }
        __syncthreads();
    }
}

__global__ __launch_bounds__(256) void zbar_kernel(unsigned* __restrict__ bstate, int total){
    const int i = blockIdx.x * 256 + threadIdx.x;
    if(i < total) bstate[i] = 0u;
}

// ==================== MEGA (persistent blocks + software barriers) ====================
struct MegaArgs {
    const void* eraw; int E; int nblk;
    int* flag;
    const float* x;
    const float* W1; const float* as1; const float* ad1; const float* b1;
    const float* W2; const float* as2; const float* ad2; const float* b2;
    const float* W3; const float* as3; const float* ad3; const float* b3;
    unsigned short* xbf;
    unsigned short* Wa1; unsigned short* Wa2; unsigned short* Wa3;
    unsigned short* Wc1; unsigned short* Wc2; unsigned short* Wc3;
    int* blkcnt; unsigned* ebuf; int* row_ptr; int* colv;
    float* eav; float* edv;
    unsigned short* g; unsigned short* h1; unsigned short* h2;
    unsigned* bslots; unsigned* bflags;
    void* out;
};

__global__ __launch_bounds__(256) void mega_kernel(MegaArgs a){
    union Smem {
        struct { int ls[4][64]; float lw[4][64][4]; } gat;
        int hist[NBUCKET];
        int cur[NBUCKET];
        int part[256];
        struct { int lcnt[128]; int lcur[128]; int sh[128]; } fin;
        unsigned short lh[4][16][72];
    };
    __shared__ Smem sm;
    const int t = threadIdx.x;
    const int wave = t >> 6;
    const int NB = a.nblk;
    const int E = a.E;
    const int mBlocks = (NNODES + 63) / 64;   // 782
    const int nGroups = NNODES / 4;           // 12500

    // ---- P0: flag detect + prep (xbf, Wa*, Wc*) ----
    if(blockIdx.x == 0 && t < 64){
        const unsigned long long v = ((const unsigned long long*)a.eraw)[t];
        const unsigned long long mask = __ballot(v >= (1ULL << 32));
        if(t == 0) *a.flag = (mask == 0ULL) ? 1 : 0;
    }
    {
        const int X4 = NNODES * 32;
        const int prepTotal = X4 + 16*128 + 16*64 + 16*64 + 64*512 + 64*256 + 48*256;
        for(int id = blockIdx.x * 256 + t; id < prepTotal; id += NB * 256)
            prep_item(id, a.x, a.xbf, X4, a.W1, a.as1, a.ad1, a.W2, a.as2, a.ad2,
                      a.W3, a.as3, a.ad3, a.Wa1, a.Wa2, a.Wa3, a.Wc1, a.Wc2, a.Wc3);
    }
    gbar(a.bslots, a.bflags, 0, NB);

    // ---- P1: bincount (blocks 0..63) || agemm layer-1 (remaining blocks) ----
    const int chunk = (E + 63) >> 6;
    if(blockIdx.x < 64){
        for(int i = t; i < NBUCKET; i += 256) sm.hist[i] = 0;
        __syncthreads();
        const bool f = (*a.flag) != 0;
        const int beg = blockIdx.x * chunk, end = min(beg + chunk, E);
        for(int i = beg + t; i < end; i += 256){
            const int d = f ? (int)((const long long*)a.eraw)[E + i] : ((const int*)a.eraw)[E + i];
            atomicAdd(&sm.hist[d >> 7], 1);
        }
        __syncthreads();
        for(int b = t; b < NBUCKET; b += 256) a.blkcnt[b * 64 + blockIdx.x] = sm.hist[b];
    } else {
        for(int mb = blockIdx.x - 64; mb < mBlocks; mb += NB - 64)
            agemm_body<128>(a.xbf, a.Wa1, a.eav, a.edv, NNODES, mb * 64);
    }
    gbar(a.bslots, a.bflags, 1, NB);

    // ---- P2: scan of blkcnt[391*64] (block 0) ----
    if(blockIdx.x == 0){
        const int total = NBUCKET * 64;
        const int per = (total + 255) / 256;
        const int beg = t * per, end = min(beg + per, total);
        int sum = 0;
        for(int i = beg; i < end; i++) sum += a.blkcnt[i];
        sm.part[t] = sum;
        __syncthreads();
        for(int off = 1; off < 256; off <<= 1){
            const int add = (t >= off) ? sm.part[t - off] : 0;
            __syncthreads();
            sm.part[t] += add;
            __syncthreads();
        }
        int run = sm.part[t] - sum;
        for(int i = beg; i < end; i++){
            const int v = a.blkcnt[i];
            a.blkcnt[i] = run;
            run += v;
        }
    }
    gbar(a.bslots, a.bflags, 2, NB);

    // ---- P3: binscatter, direct-write with LDS cursors (blocks 0..63) ----
    if(blockIdx.x < 64){
        for(int b = t; b < NBUCKET; b += 256) sm.cur[b] = a.blkcnt[b * 64 + blockIdx.x];
        __syncthreads();
        const bool f = (*a.flag) != 0;
        const int beg = blockIdx.x * chunk, end = min(beg + chunk, E);
        for(int i = beg + t; i < end; i += 256){
            int s, d;
            if(f){ s = (int)((const long long*)a.eraw)[i]; d = (int)((const long long*)a.eraw)[E + i]; }
            else { s = ((const int*)a.eraw)[i];            d = ((const int*)a.eraw)[E + i]; }
            const int b = d >> 7;
            const int p = atomicAdd(&sm.cur[b], 1);
            a.ebuf[p] = (unsigned)s | ((unsigned)(d & 127) << 16) | ((unsigned)b << 23);
        }
    }
    gbar(a.bslots, a.bflags, 3, NB);

    // ---- P4: per-bucket finalize -> row_ptr, col ----
    if(blockIdx.x == 0 && t == 0) a.row_ptr[NNODES] = E;
    for(int b = blockIdx.x; b < NBUCKET; b += NB)
        bfinal_body(a.ebuf, a.blkcnt, a.row_ptr, a.colv, NNODES, E, 64, b,
                    sm.fin.lcnt, sm.fin.lcur, sm.fin.sh);
    gbar(a.bslots, a.bflags, 4, NB);

    // ---- P5: gather layer 1 (raw x, K=128) ----
    for(int grp = blockIdx.x; grp < nGroups; grp += NB)
        gather_body<128>(a.xbf, a.row_ptr, a.colv, a.eav, a.edv, a.g,
                         grp * 4 + wave, sm.gat.ls[wave], sm.gat.lw[wave]);
    gbar(a.bslots, a.bflags, 5, NB);

    // ---- P6: pgemm1 (+alpha layer 2) ----
    for(int mb = blockIdx.x; mb < mBlocks; mb += NB)
        pgemm_body<512, 64, false, true>(a.g, a.Wc1, a.b1, a.h1, a.Wa2, a.eav, a.edv,
                                         NNODES, mb * 64 + wave * 16, sm.lh[wave]);
    gbar(a.bslots, a.bflags, 6, NB);

    // ---- P7: gather layer 2 (h1, K=64) ----
    for(int grp = blockIdx.x; grp < nGroups; grp += NB)
        gather_body<64>(a.h1, a.row_ptr, a.colv, a.eav, a.edv, a.g,
                        grp * 4 + wave, sm.gat.ls[wave], sm.gat.lw[wave]);
    gbar(a.bslots, a.bflags, 7, NB);

    // ---- P8: pgemm2 (+alpha layer 3) ----
    for(int mb = blockIdx.x; mb < mBlocks; mb += NB)
        pgemm_body<256, 64, false, true>(a.g, a.Wc2, a.b2, a.h2, a.Wa3, a.eav, a.edv,
                                         NNODES, mb * 64 + wave * 16, sm.lh[wave]);
    gbar(a.bslots, a.bflags, 8, NB);

    // ---- P9: gather layer 3 (h2, K=64) ----
    for(int grp = blockIdx.x; grp < nGroups; grp += NB)
        gather_body<64>(a.h2, a.row_ptr, a.colv, a.eav, a.edv, a.g,
                        grp * 4 + wave, sm.gat.ls[wave], sm.gat.lw[wave]);
    gbar(a.bslots, a.bflags, 9, NB);

    // ---- P10: pgemm3 + log_softmax ----
    for(int mb = blockIdx.x; mb < mBlocks; mb += NB)
        pgemm_body<256, 40, true, false>(a.g, a.Wc3, a.b3, a.out, nullptr, nullptr, nullptr,
                                         NNODES, mb * 64 + wave * 16, sm.lh[wave]);
}

// ==================== standalone fallback kernels (round-6 path) ====================

__global__ void initprep_kernel(const unsigned long long* __restrict__ e, int* __restrict__ flag,
                                const float* __restrict__ x, unsigned short* __restrict__ xbf, int X4,
                                const float* __restrict__ W1, const float* __restrict__ as1, const float* __restrict__ ad1,
                                const float* __restrict__ W2, const float* __restrict__ as2, const float* __restrict__ ad2,
                                const float* __restrict__ W3, const float* __restrict__ as3, const float* __restrict__ ad3,
                                unsigned short* __restrict__ Wa1, unsigned short* __restrict__ Wa2,
                                unsigned short* __restrict__ Wa3, unsigned short* __restrict__ Wc1,
                                unsigned short* __restrict__ Wc2, unsigned short* __restrict__ Wc3){
    if(blockIdx.x == 0 && threadIdx.x < 64){
        const unsigned long long v = e[threadIdx.x];
        const unsigned long long mask = __ballot(v >= (1ULL << 32));
        if(threadIdx.x == 0) *flag = (mask == 0ULL) ? 1 : 0;
    }
    const int id = blockIdx.x * blockDim.x + threadIdx.x;
    prep_item(id, x, xbf, X4, W1, as1, ad1, W2, as2, ad2, W3, as3, ad3,
              Wa1, Wa2, Wa3, Wc1, Wc2, Wc3);
}

__global__ __launch_bounds__(256) void bincount_kernel(const void* __restrict__ e, const int* __restrict__ flag,
                                                       int* __restrict__ blkcnt, int E, int nbin, int chunk){
    __shared__ int lcnt[NBUCKET];
    for(int i = threadIdx.x; i < NBUCKET; i += 256) lcnt[i] = 0;
    __syncthreads();
    const bool f = (*flag) != 0;
    const int beg = blockIdx.x * chunk;
    const int end = min(beg + chunk, E);
    for(int i = beg + threadIdx.x; i < end; i += 256){
        const int d = f ? (int)((const long long*)e)[E + i] : ((const int*)e)[E + i];
        atomicAdd(&lcnt[d >> 7], 1);
    }
    __syncthreads();
    for(int b = threadIdx.x; b < NBUCKET; b += 256)
        blkcnt[b * nbin + blockIdx.x] = lcnt[b];
}

__global__ __launch_bounds__(256) void binscan_kernel(int* __restrict__ blkcnt, int total){
    __shared__ int part[256];
    const int t = threadIdx.x;
    const int per = (total + 255) / 256;
    const int beg = t * per, end = min(beg + per, total);
    int sum = 0;
    for(int i = beg; i < end; i++) sum += blkcnt[i];
    part[t] = sum;
    __syncthreads();
    for(int off = 1; off < 256; off <<= 1){
        const int add = (t >= off) ? part[t - off] : 0;
        __syncthreads();
        part[t] += add;
        __syncthreads();
    }
    int run = part[t] - sum;
    for(int i = beg; i < end; i++){
        const int v = blkcnt[i];
        blkcnt[i] = run;
        run += v;
    }
}

__global__ __launch_bounds__(256) void binscatter_kernel(const void* __restrict__ e, const int* __restrict__ flag,
                                                         const int* __restrict__ blkcnt,
                                                         unsigned* __restrict__ ebuf,
                                                         int E, int nbin, int chunk){
    __shared__ int lcur[NBUCKET];
    const int t = threadIdx.x;
    for(int b = t; b < NBUCKET; b += 256) lcur[b] = blkcnt[b * nbin + blockIdx.x];
    __syncthreads();
    const bool f = (*flag) != 0;
    const int beg = blockIdx.x * chunk;
    const int end = min(beg + chunk, E);
    for(int i = beg + t; i < end; i += 256){
        int s, d;
        if(f){ s = (int)((const long long*)e)[i]; d = (int)((const long long*)e)[E + i]; }
        else { s = ((const int*)e)[i];            d = ((const int*)e)[E + i]; }
        const int b = d >> 7;
        const int p = atomicAdd(&lcur[b], 1);
        ebuf[p] = (unsigned)s | ((unsigned)(d & 127) << 16) | ((unsigned)b << 23);
    }
}

__global__ __launch_bounds__(256) void bfinal_kernel(const unsigned* __restrict__ ebuf,
                                                     const int* __restrict__ blkcnt,
                                                     int* __restrict__ row_ptr, int* __restrict__ col,
                                                     int N, int E, int nbin){
    __shared__ int lcnt[128], lcur[128], sh[128];
    if(blockIdx.x == 0 && threadIdx.x == 0) row_ptr[N] = E;
    bfinal_body(ebuf, blkcnt, row_ptr, col, N, E, nbin, blockIdx.x, lcnt, lcur, sh);
}

template<int K>
__global__ __launch_bounds__(256) void agemm_kernel(const unsigned short* __restrict__ A,
                                                    const unsigned short* __restrict__ Wa,
                                                    float* __restrict__ ea, float* __restrict__ ed,
                                                    int M){
    agemm_body<K>(A, Wa, ea, ed, M, blockIdx.x * 64);
}

template<int K>
__global__ __launch_bounds__(256) void gatherg_kernel(const unsigned short* __restrict__ X,
                                                      const int* __restrict__ row_ptr,
                                                      const int* __restrict__ col,
                                                      const float* __restrict__ ea,
                                                      const float* __restrict__ ed,
                                                      unsigned short* __restrict__ g){
    __shared__ int   ls[4][64];
    __shared__ float lw[4][64][4];
    const int wave = threadIdx.x >> 6;
    gather_body<K>(X, row_ptr, col, ea, ed, g, blockIdx.x * 4 + wave, ls[wave], lw[wave]);
}

template<int KC, int NC, bool FINAL, bool ALPHA>
__global__ __launch_bounds__(256) void pgemm_kernel(const unsigned short* __restrict__ A,
                                                    const unsigned short* __restrict__ Bt,
                                                    const float* __restrict__ bias,
                                                    void* __restrict__ outv,
                                                    const unsigned short* __restrict__ Wa,
                                                    float* __restrict__ ea,
                                                    float* __restrict__ ed,
                                                    int M){
    __shared__ unsigned short lh[ALPHA ? 4 : 1][16][72];
    const int wave = threadIdx.x >> 6;
    pgemm_body<KC, NC, FINAL, ALPHA>(A, Bt, bias, outv, Wa, ea, ed, M,
                                     blockIdx.x * 64 + wave * 16,
                                     lh[ALPHA ? wave : 0]);
}

// ---------------- driver ----------------
extern "C" void kernel_launch(void* const* d_in, const int* in_sizes, int n_in,
                              void* d_out, int out_size, void* d_ws, size_t ws_size,
                              hipStream_t stream){
    const int N = NNODES;
    const int E = in_sizes[1] / 2;

    const float* x   = (const float*)d_in[0];
    const float* W1  = (const float*)d_in[2];
    const float* as1 = (const float*)d_in[3];
    const float* ad1 = (const float*)d_in[4];
    const float* b1  = (const float*)d_in[5];
    const float* W2  = (const float*)d_in[6];
    const float* as2 = (const float*)d_in[7];
    const float* ad2 = (const float*)d_in[8];
    const float* b2  = (const float*)d_in[9];
    const float* W3  = (const float*)d_in[10];
    const float* as3 = (const float*)d_in[11];
    const float* ad3 = (const float*)d_in[12];
    const float* b3  = (const float*)d_in[13];

    char* ws = (char*)d_ws;
    size_t off = 0;
    auto alloc = [&](size_t bytes) -> void* {
        void* p = ws + off;
        off = (off + bytes + 255) & ~(size_t)255;
        return p;
    };
    int*      flag    = (int*)     alloc(4);
    int*      row_ptr = (int*)     alloc((size_t)(N + 1) * 4);
    int*      colv    = (int*)     alloc((size_t)E * 4);
    int*      blkcnt  = (int*)     alloc((size_t)NBUCKET * NBIN_MAX * 4);
    unsigned* ebuf    = (unsigned*)alloc((size_t)E * 4);
    unsigned* bstate  = (unsigned*)alloc((size_t)(MAXB * NBAR + NBAR) * 4);
    unsigned short* xbf = (unsigned short*)alloc((size_t)N * 128 * 2);
    unsigned short* Wa1 = (unsigned short*)alloc(16 * 128 * 2);
    unsigned short* Wa2 = (unsigned short*)alloc(16 * 64 * 2);
    unsigned short* Wa3 = (unsigned short*)alloc(16 * 64 * 2);
    unsigned short* Wc1 = (unsigned short*)alloc((size_t)64 * 512 * 2);
    unsigned short* Wc2 = (unsigned short*)alloc((size_t)64 * 256 * 2);
    unsigned short* Wc3 = (unsigned short*)alloc((size_t)48 * 256 * 2);
    float* eav     = (float*)alloc((size_t)N * 8 * 4);
    float* edv     = (float*)alloc((size_t)N * 8 * 4);
    unsigned short* g   = (unsigned short*)alloc((size_t)N * 512 * 2);
    unsigned short* h1  = (unsigned short*)alloc((size_t)N * 64 * 2);
    unsigned short* h2  = (unsigned short*)alloc((size_t)N * 64 * 2);
    (void)ws_size;

    const void* eraw = d_in[1];

    // ---- persistent mega-kernel with software barriers (graph-capturable) ----
    int dev = 0;
    (void)hipGetDevice(&dev);
    int maxPerCU = 0;
    if(hipOccupancyMaxActiveBlocksPerMultiprocessor(&maxPerCU, mega_kernel, 256, 0) == hipSuccess
       && maxPerCU > 0){
        int numCU = 0;
        (void)hipDeviceGetAttribute(&numCU, hipDeviceAttributeMultiprocessorCount, dev);
        int nblk = maxPerCU * numCU;
        if(nblk > MAXB) nblk = MAXB;
        if(nblk >= 256){
            const int ztotal = MAXB * NBAR + NBAR;
            zbar_kernel<<<(ztotal + 255) / 256, 256, 0, stream>>>(bstate, ztotal);
            MegaArgs ma;
            ma.eraw = eraw; ma.E = E; ma.nblk = nblk; ma.flag = flag; ma.x = x;
            ma.W1 = W1; ma.as1 = as1; ma.ad1 = ad1; ma.b1 = b1;
            ma.W2 = W2; ma.as2 = as2; ma.ad2 = ad2; ma.b2 = b2;
            ma.W3 = W3; ma.as3 = as3; ma.ad3 = ad3; ma.b3 = b3;
            ma.xbf = xbf; ma.Wa1 = Wa1; ma.Wa2 = Wa2; ma.Wa3 = Wa3;
            ma.Wc1 = Wc1; ma.Wc2 = Wc2; ma.Wc3 = Wc3;
            ma.blkcnt = blkcnt; ma.ebuf = ebuf; ma.row_ptr = row_ptr; ma.colv = colv;
            ma.eav = eav; ma.edv = edv; ma.g = g; ma.h1 = h1; ma.h2 = h2;
            ma.bslots = bstate; ma.bflags = bstate + (size_t)MAXB * NBAR;
            ma.out = d_out;
            mega_kernel<<<nblk, 256, 0, stream>>>(ma);
            return;
        }
    }

    // ---- fallback: proven round-6 multi-kernel path ----
    const int X4 = N * 128 / 4;
    const int prepTotal = X4 + 16*128 + 16*64 + 16*64 + 64*512 + 64*256 + 48*256;
    initprep_kernel<<<(prepTotal + 255) / 256, 256, 0, stream>>>(
        (const unsigned long long*)eraw, flag, x, xbf, X4,
        W1, as1, ad1, W2, as2, ad2, W3, as3, ad3,
        Wa1, Wa2, Wa3, Wc1, Wc2, Wc3);

    const int nbin = 64;
    const int chunkE = (E + nbin - 1) / nbin;
    bincount_kernel<<<nbin, 256, 0, stream>>>(eraw, flag, blkcnt, E, nbin, chunkE);
    binscan_kernel<<<1, 256, 0, stream>>>(blkcnt, NBUCKET * nbin);
    binscatter_kernel<<<nbin, 256, 0, stream>>>(eraw, flag, blkcnt, ebuf, E, nbin, chunkE);
    bfinal_kernel<<<NBUCKET, 256, 0, stream>>>(ebuf, blkcnt, row_ptr, colv, N, E, nbin);

    const int nodeBlocks = N / 4;              // 12500
    const int mBlocks = (N + 63) / 64;         // 782

    agemm_kernel<128><<<mBlocks, 256, 0, stream>>>(xbf, Wa1, eav, edv, N);
    gatherg_kernel<128><<<nodeBlocks, 256, 0, stream>>>(xbf, row_ptr, colv, eav, edv, g);
    pgemm_kernel<512, 64, false, true><<<mBlocks, 256, 0, stream>>>(g, Wc1, b1, h1, Wa2, eav, edv, N);

    gatherg_kernel<64><<<nodeBlocks, 256, 0, stream>>>(h1, row_ptr, colv, eav, edv, g);
    pgemm_kernel<256, 64, false, true><<<mBlocks, 256, 0, stream>>>(g, Wc2, b2, h2, Wa3, eav, edv, N);

    gatherg_kernel<64><<<nodeBlocks, 256, 0, stream>>>(h2, row_ptr, colv, eav, edv, g);
    pgemm_kernel<256, 40, true, false><<<mBlocks, 256, 0, stream>>>(g, Wc3, b3, d_out, nullptr, nullptr, nullptr, N);
}